// Round 14
// baseline (151.315 us; speedup 1.0000x reference)
//
#include <hip/hip_runtime.h>
#include <math.h>

namespace {
constexpr int BN = 512, HH = 64, WW = 128, CC = 3;
constexpr int OHH = 13, OWW = 26;
constexpr int NPOS = OHH * OWW;   // 338
constexpr int PCH = 26;           // slabs per theta1 chunk
constexpr int NPC = NPOS / PCH;   // 13
}

// ---------------------------------------------------------------------------
// K1: LDS-exchange LocNet + fc0 partial.
// Block = (pos, bc64). Phase 1: stage footprint (6 rows x 5 cols x 3 ch x
// 64 images, zero-padded OOB) into LDS via COALESCED flat loads (lane ~ pixel
// order). Phase 2: lane = image; read 90 values from LDS (stride 91 ->
// conflict-free), compute pooled/conv0/conv1/relu + fc0 matvec; wave w owns
// oc-octet w (weights at wave-uniform addresses via readfirstlane -> s_load).
// Phase 3: cross-wave LDS reduce (stride 33) -> part[pos][n][b] (256B lines).
// Grid XCD-swizzled: each XCD gets all pos of one bc -> 590KB row-strip in L2.
// ---------------------------------------------------------------------------
__global__ __launch_bounds__(256, 3) void k_locnet(const float* __restrict__ x,
                                                   const float* __restrict__ w0,
                                                   const float* __restrict__ w1,
                                                   const float* __restrict__ fw0,
                                                   float* __restrict__ part) {
  __shared__ float lds[6400];  // stage: 64*91=5824; reduce: 192*33=6336
  const int L = (blockIdx.x & 7) * (NPOS * 8 / 8) + (blockIdx.x >> 3);
  const int bc = L / NPOS;           // 0..7  (one bc per XCD)
  const int pos = L - bc * NPOS;     // 0..337
  const int oh = pos / OWW, ow = pos - oh * OWW;
  const int b0 = bc * 64;

  // ---- phase 1: stage. slots f = (bi, ri, s): bi<64, ri<6, s<16 (15 used) --
  for (int k = 0; k < 24; ++k) {
    const int f = threadIdx.x + (k << 8);
    const int bi = f / 96;
    const int r = f - bi * 96;
    const int ri = r >> 4, s = r & 15;
    if (s < 15) {
      const int j = s / 3, ic = s - j * 3;
      const int gr = oh * 5 - 1 + ri;
      const int gc = ow * 5 - 1 + j;
      float v = 0.f;
      if (gr >= 0 && gr < HH && gc >= 0 && gc < WW)
        v = x[(size_t)(b0 + bi) * (HH * WW * CC) + gr * (WW * CC) + gc * CC + ic];
      lds[bi * 91 + ri * 15 + s] = v;
    }
  }
  __syncthreads();

  // ---- phase 2: compute. lane = image, wave = oc-octet ----
  const int wv = __builtin_amdgcn_readfirstlane(threadIdx.x >> 6);  // 0..3
  const int bl = threadIdx.x & 63;
  float xr[90];
  {
    const int xbase = bl * 91;
#pragma unroll
    for (int t2 = 0; t2 < 90; ++t2) xr[t2] = lds[xbase + t2];
  }

  float hacc[32];
#pragma unroll
  for (int n = 0; n < 32; ++n) hacc[n] = 0.f;

  // pooled taps (TF avg_pool: zero-pad sum / valid count)
  float pooled[27];
#pragma unroll
  for (int kh = 0; kh < 3; ++kh)
#pragma unroll
    for (int kw = 0; kw < 3; ++kw) {
      const int gr = oh * 5 + kh, gc = ow * 5 + kw;
      const int rc = min(gr + 1, HH - 1) - max(gr - 1, 0) + 1;
      const int c2 = min(gc + 1, WW - 1) - max(gc - 1, 0) + 1;
      const float inv = 1.0f / (float)(rc * c2);
#pragma unroll
      for (int ic = 0; ic < 3; ++ic) {
        float s = 0.f;
#pragma unroll
        for (int dr = 0; dr < 3; ++dr)
#pragma unroll
          for (int dc = 0; dc < 3; ++dc)
            s += xr[(kh + dr) * 15 + (kw + dc) * 3 + ic];
        pooled[(kh * 3 + kw) * 3 + ic] = s * inv;
      }
    }

  // conv0 (8 oc = octet wv) + relu + fc0 matvec (rows pos*64 + oc)
  {
    float a[8] = {0.f, 0.f, 0.f, 0.f, 0.f, 0.f, 0.f, 0.f};
#pragma unroll
    for (int tap = 0; tap < 27; ++tap) {
      const float pv = pooled[tap];
      const float4 wa = *(const float4*)(w0 + tap * 32 + wv * 8);
      const float4 wb = *(const float4*)(w0 + tap * 32 + wv * 8 + 4);
      a[0] += pv * wa.x; a[1] += pv * wa.y; a[2] += pv * wa.z; a[3] += pv * wa.w;
      a[4] += pv * wb.x; a[5] += pv * wb.y; a[6] += pv * wb.z; a[7] += pv * wb.w;
    }
#pragma unroll
    for (int j = 0; j < 8; ++j) {
      const float aj = fmaxf(a[j], 0.f);
      const float* wr = fw0 + (size_t)(pos * 64 + wv * 8 + j) * 32;
#pragma unroll
      for (int q = 0; q < 8; ++q) {
        const float4 w4 = *(const float4*)(wr + q * 4);
        hacc[q * 4 + 0] += aj * w4.x; hacc[q * 4 + 1] += aj * w4.y;
        hacc[q * 4 + 2] += aj * w4.z; hacc[q * 4 + 3] += aj * w4.w;
      }
    }
  }

  // conv1 (8 oc = octet wv) + relu + fc0 matvec (rows pos*64 + 32 + oc)
  {
    float a[8] = {0.f, 0.f, 0.f, 0.f, 0.f, 0.f, 0.f, 0.f};
#pragma unroll
    for (int kh = 0; kh < 5; ++kh)
#pragma unroll
      for (int kw = 0; kw < 5; ++kw)
#pragma unroll
        for (int ic = 0; ic < 3; ++ic) {
          const float pv = xr[(kh + 1) * 15 + kw * 3 + ic];
          const int tap = (kh * 5 + kw) * 3 + ic;
          const float4 wa = *(const float4*)(w1 + tap * 32 + wv * 8);
          const float4 wb = *(const float4*)(w1 + tap * 32 + wv * 8 + 4);
          a[0] += pv * wa.x; a[1] += pv * wa.y; a[2] += pv * wa.z; a[3] += pv * wa.w;
          a[4] += pv * wb.x; a[5] += pv * wb.y; a[6] += pv * wb.z; a[7] += pv * wb.w;
        }
#pragma unroll
    for (int j = 0; j < 8; ++j) {
      const float aj = fmaxf(a[j], 0.f);
      const float* wr = fw0 + (size_t)(pos * 64 + 32 + wv * 8 + j) * 32;
#pragma unroll
      for (int q = 0; q < 8; ++q) {
        const float4 w4 = *(const float4*)(wr + q * 4);
        hacc[q * 4 + 0] += aj * w4.x; hacc[q * 4 + 1] += aj * w4.y;
        hacc[q * 4 + 2] += aj * w4.z; hacc[q * 4 + 3] += aj * w4.w;
      }
    }
  }

  // ---- phase 3: cross-wave reduce (stride-33 pad: conflict-free) ----
  __syncthreads();  // stage data dead
  if (wv > 0) {
    float* rp = &lds[(size_t)(wv - 1) * 64 * 33 + bl * 33];
#pragma unroll
    for (int n = 0; n < 32; ++n) rp[n] = hacc[n];
  }
  __syncthreads();
  if (wv == 0) {
    float* po = part + (size_t)pos * 32 * 512 + b0 + bl;
#pragma unroll
    for (int n = 0; n < 32; ++n) {
      const float s = hacc[n] + lds[bl * 33 + n] + lds[64 * 33 + bl * 33 + n] +
                      lds[128 * 33 + bl * 33 + n];
      po[(size_t)n * 512] = s;
    }
  }
}

// ---------------------------------------------------------------------------
// K2: stage-1 slab reduction: part[338][32][512] -> part2[13][32][512]
// ---------------------------------------------------------------------------
__global__ __launch_bounds__(256) void k_theta1(const float* __restrict__ part,
                                                float* __restrict__ part2) {
  const int pc = blockIdx.x >> 3;        // 0..12
  const int bcs = blockIdx.x & 7;        // 0..7
  const int lane = threadIdx.x & 63;
  const int og = threadIdx.x >> 6;       // 0..3
  const int bcol = bcs * 64 + lane;
  float acc[8] = {0.f, 0.f, 0.f, 0.f, 0.f, 0.f, 0.f, 0.f};
  const float* pp = part + ((size_t)pc * PCH * 32 + og * 8) * 512 + bcol;
  for (int pq = 0; pq < PCH; ++pq) {
#pragma unroll
    for (int j = 0; j < 8; ++j)
      acc[j] += pp[((size_t)pq * 32 + j) * 512];
  }
  float* o = part2 + ((size_t)pc * 32 + og * 8) * 512 + bcol;
#pragma unroll
  for (int j = 0; j < 8; ++j) o[(size_t)j * 512] = acc[j];
}

// ---------------------------------------------------------------------------
// K3: final reduce + bias + tanh -> hid; fc1 + tanh -> theta[512][6]
// ---------------------------------------------------------------------------
__global__ __launch_bounds__(256) void k_theta2(const float* __restrict__ part2,
                                                const float* __restrict__ b0,
                                                const float* __restrict__ w1f,
                                                const float* __restrict__ b1,
                                                float* __restrict__ theta) {
  __shared__ float hid[64][32];
  const int lane = threadIdx.x & 63;
  const int og = threadIdx.x >> 6;
  const int bcol = blockIdx.x * 64 + lane;
#pragma unroll
  for (int j = 0; j < 8; ++j) {
    const int oc = og * 8 + j;
    float s = b0[oc];
#pragma unroll
    for (int pc = 0; pc < NPC; ++pc)
      s += part2[((size_t)pc * 32 + oc) * 512 + bcol];
    hid[lane][oc] = tanhf(s);
  }
  __syncthreads();
  for (int u = threadIdx.x; u < 64 * 6; u += 256) {
    const int bl = u / 6, j = u - bl * 6;
    float s2 = b1[j];
#pragma unroll
    for (int oc = 0; oc < 32; ++oc) s2 += hid[bl][oc] * w1f[oc * 6 + j];
    theta[(blockIdx.x * 64 + bl) * 6 + j] = tanhf(s2);
  }
}

// ---------------------------------------------------------------------------
// K4: affine grid + bilinear sample (exact reference clip/extrapolate; Wd==1)
// ---------------------------------------------------------------------------
__global__ __launch_bounds__(256) void k_sample(const float* __restrict__ x,
                                                const float* __restrict__ theta,
                                                float* __restrict__ out) {
  const int b = blockIdx.x >> 3;
  const int seg = blockIdx.x & 7;
  __shared__ float th[6];
  if (threadIdx.x < 6) th[threadIdx.x] = theta[b * 6 + threadIdx.x];
  __syncthreads();
  const float t00 = th[0], t01 = th[1], t02 = th[2];
  const float t10 = th[3], t11 = th[4], t12 = th[5];
  const int idx = seg * 1024 + threadIdx.x * 4;  // pixel index within image
  const int i = idx >> 7, j0 = idx & 127;
  const float yt = (float)i * (2.0f / 63.0f) - 1.0f;
  const float* xb = x + (size_t)b * (HH * WW * CC);
  float res[12];
#pragma unroll
  for (int p = 0; p < 4; ++p) {
    const float xt = (float)(j0 + p) * (2.0f / 127.0f) - 1.0f;
    const float gx = (t00 * xt + t01 * yt + t02 + 1.0f) * 64.0f;
    const float gy = (t10 * xt + t11 * yt + t12 + 1.0f) * 32.0f;
    const float fx = floorf(gx), fy = floorf(gy);
    const float x0f = fminf(fmaxf(fx, 0.f), 126.f);
    const float x1f = fminf(fmaxf(fx + 1.f, 1.f), 127.f);
    const float y0f = fminf(fmaxf(fy, 0.f), 62.f);
    const float y1f = fminf(fmaxf(fy + 1.f, 1.f), 63.f);
    const float wx0 = x1f - gx, wx1 = gx - x0f;
    const float wy0 = y1f - gy, wy1 = gy - y0f;
    const int xi0 = (int)x0f, xi1 = (int)x1f;
    const int yi0 = (int)y0f, yi1 = (int)y1f;
    const float* q00 = xb + (yi0 * WW + xi0) * 3;
    const float* q01 = xb + (yi1 * WW + xi0) * 3;
    const float* q10 = xb + (yi0 * WW + xi1) * 3;
    const float* q11 = xb + (yi1 * WW + xi1) * 3;
#pragma unroll
    for (int c = 0; c < 3; ++c)
      res[p * 3 + c] = wx0 * (wy0 * q00[c] + wy1 * q01[c]) +
                       wx1 * (wy0 * q10[c] + wy1 * q11[c]);
  }
  float4* o = (float4*)(out + ((size_t)b * 8192 + idx) * 3);
  o[0] = make_float4(res[0], res[1], res[2], res[3]);
  o[1] = make_float4(res[4], res[5], res[6], res[7]);
  o[2] = make_float4(res[8], res[9], res[10], res[11]);
}

extern "C" void kernel_launch(void* const* d_in, const int* in_sizes, int n_in,
                              void* d_out, int out_size, void* d_ws, size_t ws_size,
                              hipStream_t stream) {
  (void)in_sizes; (void)n_in; (void)out_size; (void)ws_size;
  const float* x   = (const float*)d_in[0];
  const float* w0  = (const float*)d_in[1];
  const float* w1  = (const float*)d_in[2];
  const float* fw0 = (const float*)d_in[3];
  const float* fb0 = (const float*)d_in[4];
  const float* fw1 = (const float*)d_in[5];
  const float* fb1 = (const float*)d_in[6];
  float* outp = (float*)d_out;
  // d_out doubles as scratch: part (338*32*512 = 5,538,816 floats) +
  // part2 (13*32*512 = 212,992) = 5,751,808 <= 12,582,912 floats of d_out.
  // Fully consumed before k_sample overwrites every output element.
  float* part  = outp;
  float* part2 = outp + (size_t)NPOS * 32 * 512;
  float* theta = (float*)d_ws;  // 12 KB — survives k_sample's output writes
  k_locnet<<<NPOS * 8, 256, 0, stream>>>(x, w0, w1, fw0, part);
  k_theta1<<<NPC * 8, 256, 0, stream>>>(part, part2);
  k_theta2<<<8, 256, 0, stream>>>(part2, fb0, fw1, fb1, theta);
  k_sample<<<BN * 8, 256, 0, stream>>>(x, theta, outp);
}